// Round 12
// baseline (71.413 us; speedup 1.0000x reference)
//
#include <hip/hip_runtime.h>

// Dist_Conv2D_Dense: Chebyshev (L-inf) distance "conv".
// B=8, Cin=16, H=W=64, Cout=32, K=3, stride=1, edge-replicate pad.
// out[b][co][h][w] = max_{cin,kh,kw} |x[b][cin][clamp(h+kh-1)][clamp(w+kw-1)]
//                                    - wt[co][cin][kh][kw]|  + bias[co]
//
// Round-12: NO-LDS structure. Model from r6/r8 counters: 144 ds_read_b128
// weight broadcasts/thread saturate the LDS return path (12cyc each; 5.8us
// per CU at 8 waves, 11.5us at 16 waves) -> kernel is LDS-bound, which is
// why occupancy (r8), XCD locality (r9/10) and load pipelining (r11) were
// all neutral. Fix: block = one cout-group -> weight reads are wave-uniform
// -> scalar s_load into SGPRs (SMEM pipe, no 64-lane fanout); taps read the
// weight as the one allowed SGPR operand. x windows + weight groups double-
// buffered 1 cin ahead with static even/odd buffers. 2px x 4couts per
// thread (proven r4/r6 body), 512 blocks.

constexpr int Bn = 8, Cin = 16, Hn = 64, Wn = 64, Cout = 32;
constexpr int CPT = 4;            // couts per thread (one group per block)
constexpr int NG  = Cout / CPT;   // 8 cout groups
constexpr int BLOCK = 256;

__global__ __launch_bounds__(BLOCK, 2)   // VGPR headroom (no 128 cap): avoid r5's spill mode
void dist_conv_kernel(const float* __restrict__ x,
                      const float* __restrict__ wt,
                      const float* __restrict__ bias,
                      float* __restrict__ out) {
    const int g    = blockIdx.x & (NG - 1);   // cout group 0..7 (wave-uniform)
    const int pblk = blockIdx.x >> 3;         // pixel-pair block 0..63

    // pixel-pair id: each thread does pixels (h, w0) and (h, w0+1)
    const int p  = pblk * BLOCK + threadIdx.x;    // 0..16383
    const int w0 = (p & 31) * 2;                  // 0,2,..,62 (8B aligned)
    const int h  = (p >> 5) & 63;
    const int b  = p >> 11;

    const int hm = max(h - 1, 0) * Wn;
    const int h0 = h * Wn;
    const int hp = min(h + 1, Hn - 1) * Wn;
    const int cm = max(w0 - 1, 0);
    const int c3 = min(w0 + 2, Wn - 1);

    const float* xb = x + b * (Cin * Hn * Wn);
    const float* wb = wt + (g * CPT) * (Cin * 9);   // uniform base -> s_load

    float a0[CPT] = {0.f, 0.f, 0.f, 0.f};
    float a1[CPT] = {0.f, 0.f, 0.f, 0.f};

    float xA[3][4], xB[3][4];          // 2px 3x4 windows, double-buffered
    float wA[CPT][9], wB[CPT][9];      // uniform weight groups (SGPR-resident)

    // 12 x-values: per row 1 scalar (left edge) + float2 (center) + 1 scalar.
    auto loadX = [&](float (&xr)[3][4], int cin) {
        const float* xc = xb + cin * (Hn * Wn);
        const int ro[3] = {hm, h0, hp};
#pragma unroll
        for (int r = 0; r < 3; ++r) {
            xr[r][0] = xc[ro[r] + cm];
            const float2 m = *reinterpret_cast<const float2*>(xc + ro[r] + w0);
            xr[r][1] = m.x; xr[r][2] = m.y;
            xr[r][3] = xc[ro[r] + c3];
        }
    };
    // 36 uniform weights: consecutive 9-float runs -> merged scalar loads.
    auto loadW = [&](float (&wr)[CPT][9], int cin) {
#pragma unroll
        for (int c = 0; c < CPT; ++c) {
            const float* wc = wb + c * (Cin * 9) + cin * 9;
#pragma unroll
            for (int k = 0; k < 9; ++k) wr[c][k] = wc[k];
        }
    };
    // 9 taps x 2 px x 4 couts: v_sub_f32 (SGPR weight operand) + v_max(abs).
    auto comp = [&](const float (&xr)[3][4], const float (&wr)[CPT][9]) {
#pragma unroll
        for (int kh = 0; kh < 3; ++kh)
#pragma unroll
            for (int kw = 0; kw < 3; ++kw) {
                const float xa = xr[kh][kw];
                const float xv = xr[kh][kw + 1];
#pragma unroll
                for (int c = 0; c < CPT; ++c) {
                    const float wv = wr[c][kh * 3 + kw];
                    a0[c] = fmaxf(a0[c], fabsf(xa - wv));
                    a1[c] = fmaxf(a1[c], fabsf(xv - wv));
                }
            }
    };

    loadX(xA, 0); loadW(wA, 0);
#pragma unroll
    for (int ci = 0; ci < Cin; ci += 2) {
        if (ci + 1 < Cin) { loadX(xB, ci + 1); loadW(wB, ci + 1); }
        comp(xA, wA);
        if (ci + 2 < Cin) { loadX(xA, ci + 2); loadW(wA, ci + 2); }
        if (ci + 1 < Cin) comp(xB, wB);
    }

    float* ob = out + b * (Cout * Hn * Wn) + h0 + w0;
#pragma unroll
    for (int c = 0; c < CPT; ++c) {
        const int co = g * CPT + c;
        const float bi = bias[co];    // uniform -> s_load
        *reinterpret_cast<float2*>(ob + co * (Hn * Wn)) =
            make_float2(a0[c] + bi, a1[c] + bi);
    }
}

extern "C" void kernel_launch(void* const* d_in, const int* in_sizes, int n_in,
                              void* d_out, int out_size, void* d_ws, size_t ws_size,
                              hipStream_t stream) {
    const float* x    = (const float*)d_in[0];
    const float* wt   = (const float*)d_in[1];
    const float* bias = (const float*)d_in[2];
    float* out        = (float*)d_out;

    // grid: 8 cout-groups * (8*64*64/2 pixel-pairs / 256 threads) = 512 blocks
    const int pixel_pairs = Bn * Hn * Wn / 2;          // 16384
    const int grid = NG * (pixel_pairs / BLOCK);       // 512
    dist_conv_kernel<<<grid, BLOCK, 0, stream>>>(x, wt, bias, out);
}

// Round 13
// 69.250 us; speedup vs baseline: 1.0312x; 1.0312x over previous
//
#include <hip/hip_runtime.h>

// Dist_Conv2D_Dense: Chebyshev (L-inf) distance "conv".
// B=8, Cin=16, H=W=64, Cout=32, K=3, stride=1, edge-replicate pad.
// out[b][co][h][w] = max_{cin,kh,kw} |x[b][cin][clamp(h+kh-1)][clamp(w+kw-1)]
//                                    - wt[co][cin][kh][kw]|  + bias[co]
//
// Round-13: cold-epoch decoupling. Evidence r4-r12: warm kernel 10.6us (r6
// REPS decomposition 97 = 23 + 7*10.6) but cold ~21-26us in EVERY structure
// (occupancy/XCD/pipelining/no-LDS all neutral-or-worse) -> the harness's
// 256MB 0xAA re-poison wipes L2/L3 and the main kernel serializes ~2MB of
// first-touch HBM misses (~900cy) behind its 9-scattered-loads/cin pattern.
// Fix: dedicated streaming prefetch kernel (1 float4/thread, max MLP) warms
// L2/L3 in ~3us; main kernel (r4/r6 body, best measured) then runs ~warm.

constexpr int Bn = 8, Cin = 16, Hn = 64, Wn = 64, Cout = 32;
constexpr int CPT = 4;            // couts per thread
constexpr int NG  = Cout / CPT;   // 8 cout groups
constexpr int BLOCK = 256;

__global__ __launch_bounds__(BLOCK)
void prefetch_x(const float4* __restrict__ x) {
    // 8*16*64*64 floats = 131072 float4 = 512 blocks * 256 threads * 1 each
    const float4 v = x[blockIdx.x * BLOCK + threadIdx.x];
    // keep the load live without storing anything (errata #17 pattern)
    asm volatile("" :: "v"(v.x), "v"(v.y), "v"(v.z), "v"(v.w));
}

__global__ __launch_bounds__(BLOCK, 2)
void dist_conv_kernel(const float* __restrict__ x,
                      const float* __restrict__ wt,
                      const float* __restrict__ bias,
                      float* __restrict__ out) {
    // weights for this block's 4 couts: [cin*9 + k] -> float4 over couts
    __shared__ float4 wl[Cin * 9];

    const int g    = blockIdx.x & (NG - 1);   // cout group 0..7
    const int pblk = blockIdx.x >> 3;         // pixel-pair block

    // Stage weights: 16*9*4 = 576 floats, transposed to [cin][k][c]
    for (int i = threadIdx.x; i < Cin * 9 * CPT; i += BLOCK) {
        const int cin = i / (9 * CPT);
        const int rem = i % (9 * CPT);
        const int k   = rem / CPT;
        const int c   = rem % CPT;
        reinterpret_cast<float*>(wl)[(cin * 9 + k) * CPT + c] =
            wt[((g * CPT + c) * Cin + cin) * 9 + k];
    }
    __syncthreads();

    // pixel-pair id: each thread does pixels (h, w0) and (h, w0+1)
    const int p  = pblk * BLOCK + threadIdx.x;    // 0..16383
    const int w0 = (p & 31) * 2;                  // 0,2,..,62 (8B aligned)
    const int h  = (p >> 5) & 63;
    const int b  = p >> 11;

    const int hm = max(h - 1, 0) * Wn;
    const int h0 = h * Wn;
    const int hp = min(h + 1, Hn - 1) * Wn;
    const int cm = max(w0 - 1, 0);
    const int c3 = min(w0 + 2, Wn - 1);

    float a0[CPT], a1[CPT];
#pragma unroll
    for (int c = 0; c < CPT; ++c) { a0[c] = 0.f; a1[c] = 0.f; }

    const float* xb = x + b * (Cin * Hn * Wn);
#pragma unroll
    for (int cin = 0; cin < Cin; ++cin) {
        const float* xc = xb + cin * (Hn * Wn);
        float xr[3][4];
        {
            const int ro[3] = {hm, h0, hp};
#pragma unroll
            for (int r = 0; r < 3; ++r) {
                xr[r][0] = xc[ro[r] + cm];
                const float2 m = *reinterpret_cast<const float2*>(xc + ro[r] + w0);
                xr[r][1] = m.x; xr[r][2] = m.y;
                xr[r][3] = xc[ro[r] + c3];
            }
        }
#pragma unroll
        for (int kh = 0; kh < 3; ++kh) {
#pragma unroll
            for (int kw = 0; kw < 3; ++kw) {
                const float4 wv = wl[cin * 9 + kh * 3 + kw];
                const float xa = xr[kh][kw];       // pixel 0 tap
                const float xv = xr[kh][kw + 1];   // pixel 1 tap
                a0[0] = fmaxf(a0[0], fabsf(xa - wv.x));
                a0[1] = fmaxf(a0[1], fabsf(xa - wv.y));
                a0[2] = fmaxf(a0[2], fabsf(xa - wv.z));
                a0[3] = fmaxf(a0[3], fabsf(xa - wv.w));
                a1[0] = fmaxf(a1[0], fabsf(xv - wv.x));
                a1[1] = fmaxf(a1[1], fabsf(xv - wv.y));
                a1[2] = fmaxf(a1[2], fabsf(xv - wv.z));
                a1[3] = fmaxf(a1[3], fabsf(xv - wv.w));
            }
        }
    }

    float* ob = out + b * (Cout * Hn * Wn) + h0 + w0;
#pragma unroll
    for (int c = 0; c < CPT; ++c) {
        const int co = g * CPT + c;
        const float bi = bias[co];
        *reinterpret_cast<float2*>(ob + co * (Hn * Wn)) =
            make_float2(a0[c] + bi, a1[c] + bi);
    }
}

extern "C" void kernel_launch(void* const* d_in, const int* in_sizes, int n_in,
                              void* d_out, int out_size, void* d_ws, size_t ws_size,
                              hipStream_t stream) {
    const float* x    = (const float*)d_in[0];
    const float* wt   = (const float*)d_in[1];
    const float* bias = (const float*)d_in[2];
    float* out        = (float*)d_out;

    // 1) stream x (2MB) into L2/L3 with max memory-level parallelism
    prefetch_x<<<512, BLOCK, 0, stream>>>(reinterpret_cast<const float4*>(x));

    // 2) main kernel: 8 cout-groups * 64 pixel-pair-blocks = 512 blocks
    const int pixel_pairs = Bn * Hn * Wn / 2;          // 16384
    const int grid = NG * (pixel_pairs / BLOCK);       // 512
    dist_conv_kernel<<<grid, BLOCK, 0, stream>>>(x, wt, bias, out);
}

// Round 14
// 64.918 us; speedup vs baseline: 1.1001x; 1.0667x over previous
//
#include <hip/hip_runtime.h>

// Dist_Conv2D_Dense: Chebyshev (L-inf) distance "conv".
// B=8, Cin=16, H=W=64, Cout=32, K=3, stride=1, edge-replicate pad.
// out[b][co][h][w] = max_{cin,kh,kw} |x[b][cin][clamp(h+kh-1)][clamp(w+kw-1)]
//                                    - wt[co][cin][kh][kw]|  + bias[co]
//
// Round-14: r8 structure (best measured, 65.05) + IN-KERNEL prefetch burst.
// r13 showed a separate prefetch dispatch costs ~4-5us launch overhead and
// nets negative. Here blocks 0..511 each issue one float4 x-load (2MB total,
// 131K concurrent misses chip-wide) BEFORE weight staging and sink it after
// __syncthreads -> cold-miss epoch runs in parallel with LDS staging, zero
// extra dispatch. Everything else bit-identical to r8.

constexpr int Bn = 8, Cin = 16, Hn = 64, Wn = 64, Cout = 32;
constexpr int CPT = 4;            // couts per thread
constexpr int NG  = Cout / CPT;   // 8 cout groups
constexpr int BLOCK = 256;

__global__ __launch_bounds__(BLOCK, 4)   // 4 waves/EU min -> >=4 blocks/CU resident
void dist_conv_kernel(const float* __restrict__ x,
                      const float* __restrict__ wt,
                      const float* __restrict__ bias,
                      float* __restrict__ out) {
    // weights for this block's 4 couts: [cin*9 + k] -> float4 over couts
    __shared__ float4 wl[Cin * 9];

    // --- MLP burst: blocks 0..511 cover all of x (131072 float4 = 2MB). ---
    float4 pf = make_float4(0.f, 0.f, 0.f, 0.f);
    if (blockIdx.x < 512) {
        pf = reinterpret_cast<const float4*>(x)[blockIdx.x * BLOCK + threadIdx.x];
    }

    const int g    = blockIdx.x & (NG - 1);   // cout group 0..7
    const int pblk = blockIdx.x >> 3;         // pixel block 0..127

    // Stage weights: 16*9*4 = 576 floats, transposed to [cin][k][c]
    for (int i = threadIdx.x; i < Cin * 9 * CPT; i += BLOCK) {
        const int cin = i / (9 * CPT);
        const int rem = i % (9 * CPT);
        const int k   = rem / CPT;
        const int c   = rem % CPT;
        reinterpret_cast<float*>(wl)[(cin * 9 + k) * CPT + c] =
            wt[((g * CPT + c) * Cin + cin) * 9 + k];
    }
    __syncthreads();

    // Sink the prefetch value here: load stayed in flight across staging.
    asm volatile("" :: "v"(pf.x), "v"(pf.y), "v"(pf.z), "v"(pf.w));

    // one pixel per thread
    const int p  = pblk * BLOCK + threadIdx.x;    // 0..32767
    const int w0 = p & 63;
    const int h  = (p >> 6) & 63;
    const int b  = p >> 12;

    const int hm = max(h - 1, 0) * Wn;
    const int h0 = h * Wn;
    const int hp = min(h + 1, Hn - 1) * Wn;
    const int cm = max(w0 - 1, 0);
    const int cp = min(w0 + 1, Wn - 1);

    float acc[CPT] = {0.f, 0.f, 0.f, 0.f};

    const float* xb = x + b * (Cin * Hn * Wn);
#pragma unroll
    for (int cin = 0; cin < Cin; ++cin) {
        const float* xc = xb + cin * (Hn * Wn);
        float xr[3][3];
        xr[0][0] = xc[hm + cm]; xr[0][1] = xc[hm + w0]; xr[0][2] = xc[hm + cp];
        xr[1][0] = xc[h0 + cm]; xr[1][1] = xc[h0 + w0]; xr[1][2] = xc[h0 + cp];
        xr[2][0] = xc[hp + cm]; xr[2][1] = xc[hp + w0]; xr[2][2] = xc[hp + cp];
#pragma unroll
        for (int kh = 0; kh < 3; ++kh) {
#pragma unroll
            for (int kw = 0; kw < 3; ++kw) {
                const float4 wv = wl[cin * 9 + kh * 3 + kw];
                const float xa = xr[kh][kw];
                acc[0] = fmaxf(acc[0], fabsf(xa - wv.x));
                acc[1] = fmaxf(acc[1], fabsf(xa - wv.y));
                acc[2] = fmaxf(acc[2], fabsf(xa - wv.z));
                acc[3] = fmaxf(acc[3], fabsf(xa - wv.w));
            }
        }
    }

    float* ob = out + b * (Cout * Hn * Wn) + h0 + w0;
#pragma unroll
    for (int c = 0; c < CPT; ++c) {
        const int co = g * CPT + c;
        ob[co * (Hn * Wn)] = acc[c] + bias[co];
    }
}

extern "C" void kernel_launch(void* const* d_in, const int* in_sizes, int n_in,
                              void* d_out, int out_size, void* d_ws, size_t ws_size,
                              hipStream_t stream) {
    const float* x    = (const float*)d_in[0];
    const float* wt   = (const float*)d_in[1];
    const float* bias = (const float*)d_in[2];
    float* out        = (float*)d_out;

    // grid: 8 cout-groups * (8*64*64 pixels / 256 threads) = 8*128 = 1024 blocks
    const int pixels = Bn * Hn * Wn;               // 32768
    const int grid   = NG * (pixels / BLOCK);      // 1024
    dist_conv_kernel<<<grid, BLOCK, 0, stream>>>(x, wt, bias, out);
}